// Round 6
// baseline (532.874 us; speedup 1.0000x reference)
//
#include <hip/hip_runtime.h>

#define N 8192
#define F 128
#define NEWF 64
#define ALPHA 0.2f
#define JSPLIT 8
#define JW (N / JSPLIT)     // 1024 j per block
#define NCH (JW / 32)       // 32 chunks of K=32
#define RB 64               // rows per block (4 waves x 16)

typedef float f32x4 __attribute__((ext_vector_type(4)));
typedef short short8 __attribute__((ext_vector_type(8)));

// ---------------------------------------------------------------------------
// Kernel 0: bit-pack A into the lane-contiguous mask layout k_main consumes.
// ---------------------------------------------------------------------------
__global__ void __launch_bounds__(256) k_pack(const int* __restrict__ A,
                                              unsigned* __restrict__ mask) {
    const int t = threadIdx.x;
    const int row = blockIdx.x * 8 + (t >> 5);
    const int u = t & 31;
    const int js = u >> 2, lg = u & 3;
    const int4* src = (const int4*)(A + (size_t)row * N + js * JW + lg * 8);
    unsigned* dst = mask + (((size_t)row * JSPLIT + js) * 4 + lg) * 8;
#pragma unroll 4
    for (int c4 = 0; c4 < 8; ++c4) {
        unsigned word = 0;
#pragma unroll
        for (int k = 0; k < 4; ++k) {
            const int4* p = src + (size_t)(c4 * 4 + k) * 8;   // += c*32 ints
            int4 a0 = p[0], a1 = p[1];
            unsigned b = 0;
            b |= (a0.x != 0) ? 1u   : 0u;
            b |= (a0.y != 0) ? 2u   : 0u;
            b |= (a0.z != 0) ? 4u   : 0u;
            b |= (a0.w != 0) ? 8u   : 0u;
            b |= (a1.x != 0) ? 16u  : 0u;
            b |= (a1.y != 0) ? 32u  : 0u;
            b |= (a1.z != 0) ? 64u  : 0u;
            b |= (a1.w != 0) ? 128u : 0u;
            word |= b << (8 * k);
        }
        dst[c4] = word;
    }
}

// ---------------------------------------------------------------------------
// Kernel 1: h = X @ W (f32), s = h @ a_self, n = h @ a_neigh
// ---------------------------------------------------------------------------
__global__ void k_hsn(const float* __restrict__ X, const float* __restrict__ W,
                      const float* __restrict__ a_self, const float* __restrict__ a_neigh,
                      float* __restrict__ h, float* __restrict__ s, float* __restrict__ n) {
    int row = blockIdx.x * 4 + (threadIdx.x >> 6);
    int l = threadIdx.x & 63;
    const float* xr = X + (size_t)row * F;
    float acc = 0.0f;
#pragma unroll 8
    for (int f = 0; f < F; ++f) acc += xr[f] * W[f * NEWF + l];
    h[(size_t)row * NEWF + l] = acc;
    float ts = acc * a_self[l];
    float tn = acc * a_neigh[l];
#pragma unroll
    for (int off = 32; off; off >>= 1) {
        ts += __shfl_xor(ts, off);
        tn += __shfl_xor(tn, off);
    }
    if (l == 0) { s[row] = ts; n[row] = tn; }
}

// ---------------------------------------------------------------------------
// Kernel 2: transpose h, split into bf16 hi/lo planes hT[c][j]
// ---------------------------------------------------------------------------
__global__ void k_tr(const float* __restrict__ h, unsigned short* __restrict__ hThi,
                     unsigned short* __restrict__ hTlo) {
    __shared__ float tile[64][65];
    const int t = threadIdx.x;
    const int j0 = blockIdx.x * 64;
    {
        const int jr = t >> 2, cs = (t & 3) * 16;
        const float4* src = (const float4*)(h + (size_t)(j0 + jr) * NEWF + cs);
#pragma unroll
        for (int q = 0; q < 4; ++q) {
            float4 v = src[q];
            tile[jr][cs + q * 4 + 0] = v.x; tile[jr][cs + q * 4 + 1] = v.y;
            tile[jr][cs + q * 4 + 2] = v.z; tile[jr][cs + q * 4 + 3] = v.w;
        }
    }
    __syncthreads();
    {
        const int c = t >> 2, js = (t & 3) * 16;
        short8 hi0 = {}, hi1 = {}, lo0 = {}, lo1 = {};
#pragma unroll
        for (int k = 0; k < 16; ++k) {
            float v = tile[js + k][c];
            unsigned xb = __float_as_uint(v);
            short hb = (short)(xb >> 16);
            float lof = v - __uint_as_float(xb & 0xffff0000u);
            short lb = (short)(__float_as_uint(lof) >> 16);
            if (k < 8) { hi0[k] = hb; lo0[k] = lb; }
            else       { hi1[k - 8] = hb; lo1[k - 8] = lb; }
        }
        size_t off = (size_t)c * N + j0 + js;
        *(short8*)(hThi + off)     = hi0;
        *(short8*)(hThi + off + 8) = hi1;
        *(short8*)(hTlo + off)     = lo0;
        *(short8*)(hTlo + off + 8) = lo1;
    }
}

// ---------------------------------------------------------------------------
// Kernel 3: nmax = max_j n[j]
// ---------------------------------------------------------------------------
__global__ void k_nmax(const float* __restrict__ n, float* __restrict__ nmax) {
    __shared__ float red[1024];
    int t = threadIdx.x;
    float4 v0 = ((const float4*)n)[t];
    float4 v1 = ((const float4*)n)[t + 1024];
    float m = fmaxf(fmaxf(fmaxf(v0.x, v0.y), fmaxf(v0.z, v0.w)),
                    fmaxf(fmaxf(v1.x, v1.y), fmaxf(v1.z, v1.w)));
    red[t] = m;
    __syncthreads();
    for (int off = 512; off; off >>= 1) {
        if (t < off) red[t] = fmaxf(red[t], red[t + off]);
        __syncthreads();
    }
    if (t == 0) nmax[0] = red[0];
}

// ---------------------------------------------------------------------------
// Kernel 4: fused attention, split-bf16 MFMA. NO LDS, NO barriers.
//   B-fragments load directly from L2-resident hT planes (2 MB), with a
//   1-chunk rotating register prefetch pinned by sched_barrier(0).
//   All 4 waves of a block read the same B tile -> L1 catches the reuse.
//   A arrives as an 8 MB bitmask (32 B per lane per j-slice).
// ---------------------------------------------------------------------------
__global__ void __launch_bounds__(256, 4) k_main(
        const unsigned* __restrict__ mask, const float* __restrict__ s,
        const float* __restrict__ n, const float* __restrict__ nmaxp,
        const unsigned short* __restrict__ hThi, const unsigned short* __restrict__ hTlo,
        float* __restrict__ pacc, float* __restrict__ pz) {
    const int tid = threadIdx.x;
    const int w = tid >> 6, l = tid & 63;
    const int lr = l & 15, lg = l >> 4;

    const int rb = blockIdx.x / JSPLIT;
    const int js = blockIdx.x % JSPLIT;
    const int r0 = rb * RB + w * 16;
    const int jb = js * JW;

    const float sval = s[r0 + lr];
    const float tM = sval + nmaxp[0];
    const float Mv = fmaxf(tM, ALPHA * tM);
    float zacc = 0.0f;

    f32x4 acc0 = {0.f,0.f,0.f,0.f}, acc1 = {0.f,0.f,0.f,0.f};
    f32x4 acc2 = {0.f,0.f,0.f,0.f}, acc3 = {0.f,0.f,0.f,0.f};

    // per-lane B-fragment bases (short8 = 16B = one b128 per chunk each)
    const short8* gB0h = (const short8*)(hThi + (size_t)(lr +  0) * N + jb + lg * 8);
    const short8* gB1h = (const short8*)(hThi + (size_t)(lr + 16) * N + jb + lg * 8);
    const short8* gB2h = (const short8*)(hThi + (size_t)(lr + 32) * N + jb + lg * 8);
    const short8* gB3h = (const short8*)(hThi + (size_t)(lr + 48) * N + jb + lg * 8);
    const short8* gB0l = (const short8*)(hTlo + (size_t)(lr +  0) * N + jb + lg * 8);
    const short8* gB1l = (const short8*)(hTlo + (size_t)(lr + 16) * N + jb + lg * 8);
    const short8* gB2l = (const short8*)(hTlo + (size_t)(lr + 32) * N + jb + lg * 8);
    const short8* gB3l = (const short8*)(hTlo + (size_t)(lr + 48) * N + jb + lg * 8);
    const float4* npv = (const float4*)(n + jb + lg * 8);

    // per-lane mask word stream: 8 uints cover the whole 1024-j slice
    const unsigned* mp = mask + (((size_t)(r0 + lr) * JSPLIT + js) * 4 + lg) * 8;
    unsigned mpref = mp[0];

    // ---- prologue: load chunk 0's fragments ----
    short8 B0h = gB0h[0], B1h = gB1h[0], B2h = gB2h[0], B3h = gB3h[0];
    short8 B0l = gB0l[0], B1l = gB1l[0], B2l = gB2l[0], B3l = gB3l[0];
    float4 nv0 = npv[0], nv1 = npv[1];
    unsigned mword = 0;

    for (int c = 0; c < NCH; ++c) {
        const int cn = (c + 1 < NCH) ? c + 1 : 0;   // wrap: dummy on last iter

        // ---- rotate mask word every 4 chunks; prefetch the next one ----
        if ((c & 3) == 0) {
            mword = mpref;
            mpref = mp[((c >> 2) + 1) & 7];          // wrap: dummy reload
        }
        const unsigned mbyte = (mword >> ((c & 3) * 8)) & 0xffu;

        // ---- issue next-chunk loads FIRST; pin above the compute ----
        short8 nB0h = gB0h[cn * 4], nB1h = gB1h[cn * 4];
        short8 nB2h = gB2h[cn * 4], nB3h = gB3h[cn * 4];
        short8 nB0l = gB0l[cn * 4], nB1l = gB1l[cn * 4];
        short8 nB2l = gB2l[cn * 4], nB3l = gB3l[cn * 4];
        float4 nn0 = npv[cn * 8], nn1 = npv[cn * 8 + 1];
        __builtin_amdgcn_sched_barrier(0);

        // ---- e-phase: 8 e's per lane straight into A-fragments ----
        float nf[8] = {nv0.x, nv0.y, nv0.z, nv0.w, nv1.x, nv1.y, nv1.z, nv1.w};
        short8 ahi, alo;
#pragma unroll
        for (int j = 0; j < 8; ++j) {
            float t  = sval + nf[j];
            float lv = fmaxf(t, ALPHA * t);
            float ex = __expf(lv - Mv);
            ex = (mbyte & (1u << j)) ? ex : 0.0f;
            zacc += ex;
            unsigned xb = __float_as_uint(ex);
            ahi[j] = (short)(xb >> 16);
            float lof = ex - __uint_as_float(xb & 0xffff0000u);
            alo[j] = (short)(__float_as_uint(lof) >> 16);
        }

        // ---- 12 MFMAs: hi*hi + hi*lo + lo*hi ----
        acc0 = __builtin_amdgcn_mfma_f32_16x16x32_bf16(ahi, B0h, acc0, 0, 0, 0);
        acc1 = __builtin_amdgcn_mfma_f32_16x16x32_bf16(ahi, B1h, acc1, 0, 0, 0);
        acc2 = __builtin_amdgcn_mfma_f32_16x16x32_bf16(ahi, B2h, acc2, 0, 0, 0);
        acc3 = __builtin_amdgcn_mfma_f32_16x16x32_bf16(ahi, B3h, acc3, 0, 0, 0);
        acc0 = __builtin_amdgcn_mfma_f32_16x16x32_bf16(ahi, B0l, acc0, 0, 0, 0);
        acc1 = __builtin_amdgcn_mfma_f32_16x16x32_bf16(ahi, B1l, acc1, 0, 0, 0);
        acc2 = __builtin_amdgcn_mfma_f32_16x16x32_bf16(ahi, B2l, acc2, 0, 0, 0);
        acc3 = __builtin_amdgcn_mfma_f32_16x16x32_bf16(ahi, B3l, acc3, 0, 0, 0);
        acc0 = __builtin_amdgcn_mfma_f32_16x16x32_bf16(alo, B0h, acc0, 0, 0, 0);
        acc1 = __builtin_amdgcn_mfma_f32_16x16x32_bf16(alo, B1h, acc1, 0, 0, 0);
        acc2 = __builtin_amdgcn_mfma_f32_16x16x32_bf16(alo, B2h, acc2, 0, 0, 0);
        acc3 = __builtin_amdgcn_mfma_f32_16x16x32_bf16(alo, B3h, acc3, 0, 0, 0);
        __builtin_amdgcn_sched_barrier(0);

        // ---- rotate prefetch ----
        B0h = nB0h; B1h = nB1h; B2h = nB2h; B3h = nB3h;
        B0l = nB0l; B1l = nB1l; B2l = nB2l; B3l = nB3l;
        nv0 = nn0;  nv1 = nn1;
    }

    // ---- z reduce over the 4 k-groups of each row ----
    zacc += __shfl_xor(zacc, 16);
    zacc += __shfl_xor(zacc, 32);

    // ---- write partials ----
    float* pa = pacc + ((size_t)js * N + r0) * NEWF;
#pragma unroll
    for (int r = 0; r < 4; ++r) {
        int row = lg * 4 + r;
        pa[(size_t)row * NEWF +  0 + lr] = acc0[r];
        pa[(size_t)row * NEWF + 16 + lr] = acc1[r];
        pa[(size_t)row * NEWF + 32 + lr] = acc2[r];
        pa[(size_t)row * NEWF + 48 + lr] = acc3[r];
    }
    if (l < 16) pz[(size_t)js * N + r0 + lr] = zacc;
}

// ---------------------------------------------------------------------------
// Kernel 5: finalize — sum partials, divide, relu
// ---------------------------------------------------------------------------
__global__ void k_fin(const float* __restrict__ pacc, const float* __restrict__ pz,
                      float* __restrict__ out) {
    int t = blockIdx.x * 256 + threadIdx.x;     // 0 .. N*NEWF-1
    int i = t >> 6, k = t & 63;
    float v = 0.0f, z = 0.0f;
#pragma unroll
    for (int psl = 0; psl < JSPLIT; ++psl) {
        v += pacc[((size_t)psl * N + i) * NEWF + k];
        z += pz[(size_t)psl * N + i];
    }
    out[t] = fmaxf(v / z, 0.0f);
}

// ---------------------------------------------------------------------------
extern "C" void kernel_launch(void* const* d_in, const int* in_sizes, int n_in,
                              void* d_out, int out_size, void* d_ws, size_t ws_size,
                              hipStream_t stream) {
    const float* X       = (const float*)d_in[0];
    const int*   A       = (const int*)d_in[1];
    const float* W       = (const float*)d_in[2];
    const float* a_self  = (const float*)d_in[3];
    const float* a_neigh = (const float*)d_in[4];
    float* out = (float*)d_out;

    float* wsf = (float*)d_ws;
    float* h    = wsf;                        // N*NEWF f32 (2MB)
    float* s    = h + (size_t)N * NEWF;       // N
    float* nv   = s + N;                      // N
    float* nmax = nv + N;                     // 4
    unsigned short* hThi = (unsigned short*)(nmax + 4);   // N*NEWF ushort (1MB)
    unsigned short* hTlo = hThi + (size_t)N * NEWF;       // N*NEWF ushort (1MB)
    float* pacc = (float*)(hTlo + (size_t)N * NEWF);      // JSPLIT*N*NEWF f32 (16MB)
    float* pz   = pacc + (size_t)JSPLIT * N * NEWF;       // JSPLIT*N f32 (256KB)
    unsigned* mask = (unsigned*)(pz + (size_t)JSPLIT * N); // N*N/32 uints (8MB)

    k_pack<<<N / 8,        256, 0, stream>>>(A, mask);
    k_hsn <<<N / 4,        256, 0, stream>>>(X, W, a_self, a_neigh, h, s, nv);
    k_tr  <<<N / 64,       256, 0, stream>>>(h, hThi, hTlo);
    k_nmax<<<1,           1024, 0, stream>>>(nv, nmax);
    k_main<<<(N / RB) * JSPLIT, 256, 0, stream>>>(mask, s, nv, nmax, hThi, hTlo, pacc, pz);
    k_fin <<<(N * NEWF) / 256, 256, 0, stream>>>(pacc, pz, out);
}

// Round 8
// 425.075 us; speedup vs baseline: 1.2536x; 1.2536x over previous
//
#include <hip/hip_runtime.h>

#define N 8192
#define F 128
#define NEWF 64
#define ALPHA 0.2f
#define JSPLIT 8
#define JW (N / JSPLIT)     // 1024 j per block
#define RB 64               // rows per block (4 waves x 16)
#define PIECE 128           // j's staged per sync (4 chunks of K=32)
#define NPIECE (JW / PIECE) // 8

typedef float f32x4 __attribute__((ext_vector_type(4)));
typedef short short8 __attribute__((ext_vector_type(8)));

typedef const __attribute__((address_space(1))) unsigned* gp_t;
typedef __attribute__((address_space(3))) unsigned* lp_t;
static __device__ __forceinline__ void gload_lds16(const void* g, void* l) {
    __builtin_amdgcn_global_load_lds((gp_t)g, (lp_t)l, 16, 0, 0);
}

// ---------------------------------------------------------------------------
// Kernel 1: h = X @ W (f32), s = h @ a_self, n = h @ a_neigh
// ---------------------------------------------------------------------------
__global__ void k_hsn(const float* __restrict__ X, const float* __restrict__ W,
                      const float* __restrict__ a_self, const float* __restrict__ a_neigh,
                      float* __restrict__ h, float* __restrict__ s, float* __restrict__ n) {
    int row = blockIdx.x * 4 + (threadIdx.x >> 6);
    int l = threadIdx.x & 63;
    const float* xr = X + (size_t)row * F;
    float acc = 0.0f;
#pragma unroll 8
    for (int f = 0; f < F; ++f) acc += xr[f] * W[f * NEWF + l];
    h[(size_t)row * NEWF + l] = acc;
    float ts = acc * a_self[l];
    float tn = acc * a_neigh[l];
#pragma unroll
    for (int off = 32; off; off >>= 1) {
        ts += __shfl_xor(ts, off);
        tn += __shfl_xor(tn, off);
    }
    if (l == 0) { s[row] = ts; n[row] = tn; }
}

// ---------------------------------------------------------------------------
// Kernel 2: transpose h, split into bf16 hi/lo planes hT[c][j]
// ---------------------------------------------------------------------------
__global__ void k_tr(const float* __restrict__ h, unsigned short* __restrict__ hThi,
                     unsigned short* __restrict__ hTlo) {
    __shared__ float tile[64][65];
    const int t = threadIdx.x;
    const int j0 = blockIdx.x * 64;
    {
        const int jr = t >> 2, cs = (t & 3) * 16;
        const float4* src = (const float4*)(h + (size_t)(j0 + jr) * NEWF + cs);
#pragma unroll
        for (int q = 0; q < 4; ++q) {
            float4 v = src[q];
            tile[jr][cs + q * 4 + 0] = v.x; tile[jr][cs + q * 4 + 1] = v.y;
            tile[jr][cs + q * 4 + 2] = v.z; tile[jr][cs + q * 4 + 3] = v.w;
        }
    }
    __syncthreads();
    {
        const int c = t >> 2, js = (t & 3) * 16;
        short8 hi0 = {}, hi1 = {}, lo0 = {}, lo1 = {};
#pragma unroll
        for (int k = 0; k < 16; ++k) {
            float v = tile[js + k][c];
            unsigned xb = __float_as_uint(v);
            short hb = (short)(xb >> 16);
            float lof = v - __uint_as_float(xb & 0xffff0000u);
            short lb = (short)(__float_as_uint(lof) >> 16);
            if (k < 8) { hi0[k] = hb; lo0[k] = lb; }
            else       { hi1[k - 8] = hb; lo1[k - 8] = lb; }
        }
        size_t off = (size_t)c * N + j0 + js;
        *(short8*)(hThi + off)     = hi0;
        *(short8*)(hThi + off + 8) = hi1;
        *(short8*)(hTlo + off)     = lo0;
        *(short8*)(hTlo + off + 8) = lo1;
    }
}

// ---------------------------------------------------------------------------
// Kernel 3: nmax = max_j n[j]
// ---------------------------------------------------------------------------
__global__ void k_nmax(const float* __restrict__ n, float* __restrict__ nmax) {
    __shared__ float red[1024];
    int t = threadIdx.x;
    float4 v0 = ((const float4*)n)[t];
    float4 v1 = ((const float4*)n)[t + 1024];
    float m = fmaxf(fmaxf(fmaxf(v0.x, v0.y), fmaxf(v0.z, v0.w)),
                    fmaxf(fmaxf(v1.x, v1.y), fmaxf(v1.z, v1.w)));
    red[t] = m;
    __syncthreads();
    for (int off = 512; off; off >>= 1) {
        if (t < off) red[t] = fmaxf(red[t], red[t + off]);
        __syncthreads();
    }
    if (t == 0) nmax[0] = red[0];
}

// ---------------------------------------------------------------------------
// Kernel 4: fused attention. Piece-staged LDS slab via global_load_lds:
//   stage 32 KB (2 planes x 64 c x 128 j, XOR-swizzled source, linear dest),
//   vmcnt(0)+barrier, then 4 chunks barrier-free (swizzled ds_read_b128,
//   e-phase in regs, 12 MFMAs, rotating 1-chunk A/n register prefetch).
//   2 barriers per 4 chunks instead of per chunk. A read raw (overlaps).
// ---------------------------------------------------------------------------
__global__ void __launch_bounds__(256, 4) k_main(
        const int* __restrict__ A, const float* __restrict__ s,
        const float* __restrict__ n, const float* __restrict__ nmaxp,
        const unsigned short* __restrict__ hThi, const unsigned short* __restrict__ hTlo,
        float* __restrict__ pacc, float* __restrict__ pz) {
    __shared__ __align__(16) unsigned short slab[16384];   // 32 KB [pl][64][128]

    const int tid = threadIdx.x;
    const int w = tid >> 6, l = tid & 63;
    const int lr = l & 15, lg = l >> 4;

    const int rb = blockIdx.x / JSPLIT;
    const int js = blockIdx.x % JSPLIT;
    const int r0 = rb * RB + w * 16;
    const int jb = js * JW;

    const float sval = s[r0 + lr];
    const float tM = sval + nmaxp[0];
    const float Mv = fmaxf(tM, ALPHA * tM);
    float zacc = 0.0f;

    f32x4 acc0 = {0.f,0.f,0.f,0.f}, acc1 = {0.f,0.f,0.f,0.f};
    f32x4 acc2 = {0.f,0.f,0.f,0.f}, acc3 = {0.f,0.f,0.f,0.f};

    // ---- staging constants: thread t stages rows (q&3)*16 + (t>>4),
    //      16B granule (t&15), source pre-swizzled so linear LDS + swizzled
    //      read give back the true value (both-sides involution). ----
    const int sr_lo = tid >> 4;                                   // 0..15
    const int s_jsh = (((tid & 15) * 16) ^ ((sr_lo & 7) << 4)) >> 1;  // shorts
    char* slabc = (char*)slab;
    const int rswz = (lr & 7) << 4;                               // read-side XOR

#define STAGE(piece)                                                          \
    {                                                                         \
        const size_t gcol = (size_t)jb + (size_t)(piece) * PIECE + s_jsh;     \
        _Pragma("unroll")                                                     \
        for (int q = 0; q < 8; ++q) {                                         \
            const int r_ = (q & 3) * 16 + sr_lo;                              \
            const unsigned short* gp_ =                                       \
                ((q >> 2) ? hTlo : hThi) + (size_t)r_ * N + gcol;             \
            gload_lds16(gp_, slabc + q * 4096 + tid * 16);                    \
        }                                                                     \
    }

    const int4*   Ap  = (const int4*)(A + (size_t)(r0 + lr) * N + jb + lg * 8);
    const float4* npv = (const float4*)(n + jb + lg * 8);

    // ---- prologue: stage piece 0, load chunk 0's A/n ----
    STAGE(0);
    int4 a0 = Ap[0], a1 = Ap[1];
    float4 nv0 = npv[0], nv1 = npv[1];
    asm volatile("s_waitcnt vmcnt(0)" ::: "memory");
    __builtin_amdgcn_s_barrier();
    __builtin_amdgcn_sched_barrier(0);

    for (int piece = 0; piece < NPIECE; ++piece) {
#pragma unroll
        for (int k = 0; k < 4; ++k) {
            const int ci = piece * 4 + k;
            const int cn = (ci + 1 < NPIECE * 4) ? ci + 1 : 0;  // wrap: dummy

            // ---- issue next-chunk A/n loads FIRST; pin above compute ----
            int4 na0 = Ap[(size_t)cn * 8], na1 = Ap[(size_t)cn * 8 + 1];
            float4 nn0 = npv[(size_t)cn * 8], nn1 = npv[(size_t)cn * 8 + 1];
            __builtin_amdgcn_sched_barrier(0);

            // ---- e-phase: 8 e's per lane straight into A-fragments ----
            int   av[8] = {a0.x, a0.y, a0.z, a0.w, a1.x, a1.y, a1.z, a1.w};
            float nf[8] = {nv0.x, nv0.y, nv0.z, nv0.w, nv1.x, nv1.y, nv1.z, nv1.w};
            short8 ahi, alo;
#pragma unroll
            for (int j = 0; j < 8; ++j) {
                float t  = sval + nf[j];
                float lv = fmaxf(t, ALPHA * t);
                float ex = __expf(lv - Mv);
                ex = (av[j] != 0) ? ex : 0.0f;
                zacc += ex;
                unsigned xb = __float_as_uint(ex);
                ahi[j] = (short)(xb >> 16);
                float lof = ex - __uint_as_float(xb & 0xffff0000u);
                alo[j] = (short)(__float_as_uint(lof) >> 16);
            }

            // ---- B fragments from LDS (swizzled, conflict-free b128) ----
            const int joff = (k * 64 + lg * 16) ^ rswz;
            const char* rp = (const char*)slab + lr * 256 + joff;
            short8 B0h = *(const short8*)(rp);
            short8 B1h = *(const short8*)(rp + 16 * 256);
            short8 B2h = *(const short8*)(rp + 32 * 256);
            short8 B3h = *(const short8*)(rp + 48 * 256);
            short8 B0l = *(const short8*)(rp + 16384);
            short8 B1l = *(const short8*)(rp + 16384 + 16 * 256);
            short8 B2l = *(const short8*)(rp + 16384 + 32 * 256);
            short8 B3l = *(const short8*)(rp + 16384 + 48 * 256);

            // ---- 12 MFMAs: hi*hi + hi*lo + lo*hi ----
            acc0 = __builtin_amdgcn_mfma_f32_16x16x32_bf16(ahi, B0h, acc0, 0, 0, 0);
            acc1 = __builtin_amdgcn_mfma_f32_16x16x32_bf16(ahi, B1h, acc1, 0, 0, 0);
            acc2 = __builtin_amdgcn_mfma_f32_16x16x32_bf16(ahi, B2h, acc2, 0, 0, 0);
            acc3 = __builtin_amdgcn_mfma_f32_16x16x32_bf16(ahi, B3h, acc3, 0, 0, 0);
            acc0 = __builtin_amdgcn_mfma_f32_16x16x32_bf16(ahi, B0l, acc0, 0, 0, 0);
            acc1 = __builtin_amdgcn_mfma_f32_16x16x32_bf16(ahi, B1l, acc1, 0, 0, 0);
            acc2 = __builtin_amdgcn_mfma_f32_16x16x32_bf16(ahi, B2l, acc2, 0, 0, 0);
            acc3 = __builtin_amdgcn_mfma_f32_16x16x32_bf16(ahi, B3l, acc3, 0, 0, 0);
            acc0 = __builtin_amdgcn_mfma_f32_16x16x32_bf16(alo, B0h, acc0, 0, 0, 0);
            acc1 = __builtin_amdgcn_mfma_f32_16x16x32_bf16(alo, B1h, acc1, 0, 0, 0);
            acc2 = __builtin_amdgcn_mfma_f32_16x16x32_bf16(alo, B2h, acc2, 0, 0, 0);
            acc3 = __builtin_amdgcn_mfma_f32_16x16x32_bf16(alo, B3h, acc3, 0, 0, 0);

            a0 = na0; a1 = na1; nv0 = nn0; nv1 = nn1;
        }

        // ---- piece boundary: readers done -> restage -> ready ----
        if (piece + 1 < NPIECE) {
            __builtin_amdgcn_s_barrier();           // all waves done reading
            __builtin_amdgcn_sched_barrier(0);
            STAGE(piece + 1);
            asm volatile("s_waitcnt vmcnt(0)" ::: "memory");
            __builtin_amdgcn_s_barrier();           // slab fully written
            __builtin_amdgcn_sched_barrier(0);
        }
    }
#undef STAGE

    // ---- z reduce over the 4 k-groups of each row ----
    zacc += __shfl_xor(zacc, 16);
    zacc += __shfl_xor(zacc, 32);

    // ---- write partials ----
    float* pa = pacc + ((size_t)js * N + r0) * NEWF;
#pragma unroll
    for (int r = 0; r < 4; ++r) {
        int row = lg * 4 + r;
        pa[(size_t)row * NEWF +  0 + lr] = acc0[r];
        pa[(size_t)row * NEWF + 16 + lr] = acc1[r];
        pa[(size_t)row * NEWF + 32 + lr] = acc2[r];
        pa[(size_t)row * NEWF + 48 + lr] = acc3[r];
    }
    if (l < 16) pz[(size_t)js * N + r0 + lr] = zacc;
}

// ---------------------------------------------------------------------------
// Kernel 5: finalize — sum partials, divide, relu
// ---------------------------------------------------------------------------
__global__ void k_fin(const float* __restrict__ pacc, const float* __restrict__ pz,
                      float* __restrict__ out) {
    int t = blockIdx.x * 256 + threadIdx.x;     // 0 .. N*NEWF-1
    int i = t >> 6, k = t & 63;
    float v = 0.0f, z = 0.0f;
#pragma unroll
    for (int psl = 0; psl < JSPLIT; ++psl) {
        v += pacc[((size_t)psl * N + i) * NEWF + k];
        z += pz[(size_t)psl * N + i];
    }
    out[t] = fmaxf(v / z, 0.0f);
}

// ---------------------------------------------------------------------------
extern "C" void kernel_launch(void* const* d_in, const int* in_sizes, int n_in,
                              void* d_out, int out_size, void* d_ws, size_t ws_size,
                              hipStream_t stream) {
    const float* X       = (const float*)d_in[0];
    const int*   A       = (const int*)d_in[1];
    const float* W       = (const float*)d_in[2];
    const float* a_self  = (const float*)d_in[3];
    const float* a_neigh = (const float*)d_in[4];
    float* out = (float*)d_out;

    float* wsf = (float*)d_ws;
    float* h    = wsf;                        // N*NEWF f32 (2MB)
    float* s    = h + (size_t)N * NEWF;       // N
    float* nv   = s + N;                      // N
    float* nmax = nv + N;                     // 4
    unsigned short* hThi = (unsigned short*)(nmax + 4);   // N*NEWF ushort (1MB)
    unsigned short* hTlo = hThi + (size_t)N * NEWF;       // N*NEWF ushort (1MB)
    float* pacc = (float*)(hTlo + (size_t)N * NEWF);      // JSPLIT*N*NEWF f32 (16MB)
    float* pz   = pacc + (size_t)JSPLIT * N * NEWF;       // JSPLIT*N f32 (256KB)

    k_hsn <<<N / 4,        256, 0, stream>>>(X, W, a_self, a_neigh, h, s, nv);
    k_tr  <<<N / 64,       256, 0, stream>>>(h, hThi, hTlo);
    k_nmax<<<1,           1024, 0, stream>>>(nv, nmax);
    k_main<<<(N / RB) * JSPLIT, 256, 0, stream>>>(A, s, nv, nmax, hThi, hTlo, pacc, pz);
    k_fin <<<(N * NEWF) / 256, 256, 0, stream>>>(pacc, pz, out);
}

// Round 9
// 420.085 us; speedup vs baseline: 1.2685x; 1.0119x over previous
//
#include <hip/hip_runtime.h>

#define N 8192
#define F 128
#define NEWF 64
#define ALPHA 0.2f
#define JSPLIT 4
#define JW (N / JSPLIT)      // 2048 j per block
#define RB 64                // rows per block (4 waves x 16)
#define PIECE 64             // j's per stage step (2 chunks of K=32)
#define NP (JW / PIECE)      // 32 pieces

typedef float f32x4 __attribute__((ext_vector_type(4)));
typedef short short8 __attribute__((ext_vector_type(8)));

typedef const __attribute__((address_space(1))) unsigned* gp_t;
typedef __attribute__((address_space(3))) unsigned* lp_t;
static __device__ __forceinline__ void gload_lds16(const void* g, void* l) {
    __builtin_amdgcn_global_load_lds((gp_t)g, (lp_t)l, 16, 0, 0);
}

// ---------------------------------------------------------------------------
// Kernel 1: h = X @ W (f32), s = h @ a_self, n = h @ a_neigh
// ---------------------------------------------------------------------------
__global__ void k_hsn(const float* __restrict__ X, const float* __restrict__ W,
                      const float* __restrict__ a_self, const float* __restrict__ a_neigh,
                      float* __restrict__ h, float* __restrict__ s, float* __restrict__ n) {
    int row = blockIdx.x * 4 + (threadIdx.x >> 6);
    int l = threadIdx.x & 63;
    const float* xr = X + (size_t)row * F;
    float acc = 0.0f;
#pragma unroll 8
    for (int f = 0; f < F; ++f) acc += xr[f] * W[f * NEWF + l];
    h[(size_t)row * NEWF + l] = acc;
    float ts = acc * a_self[l];
    float tn = acc * a_neigh[l];
#pragma unroll
    for (int off = 32; off; off >>= 1) {
        ts += __shfl_xor(ts, off);
        tn += __shfl_xor(tn, off);
    }
    if (l == 0) { s[row] = ts; n[row] = tn; }
}

// ---------------------------------------------------------------------------
// Kernel 2: transpose h, split into bf16 hi/lo planes hT[c][j]
// ---------------------------------------------------------------------------
__global__ void k_tr(const float* __restrict__ h, unsigned short* __restrict__ hThi,
                     unsigned short* __restrict__ hTlo) {
    __shared__ float tile[64][65];
    const int t = threadIdx.x;
    const int j0 = blockIdx.x * 64;
    {
        const int jr = t >> 2, cs = (t & 3) * 16;
        const float4* src = (const float4*)(h + (size_t)(j0 + jr) * NEWF + cs);
#pragma unroll
        for (int q = 0; q < 4; ++q) {
            float4 v = src[q];
            tile[jr][cs + q * 4 + 0] = v.x; tile[jr][cs + q * 4 + 1] = v.y;
            tile[jr][cs + q * 4 + 2] = v.z; tile[jr][cs + q * 4 + 3] = v.w;
        }
    }
    __syncthreads();
    {
        const int c = t >> 2, js = (t & 3) * 16;
        short8 hi0 = {}, hi1 = {}, lo0 = {}, lo1 = {};
#pragma unroll
        for (int k = 0; k < 16; ++k) {
            float v = tile[js + k][c];
            unsigned xb = __float_as_uint(v);
            short hb = (short)(xb >> 16);
            float lof = v - __uint_as_float(xb & 0xffff0000u);
            short lb = (short)(__float_as_uint(lof) >> 16);
            if (k < 8) { hi0[k] = hb; lo0[k] = lb; }
            else       { hi1[k - 8] = hb; lo1[k - 8] = lb; }
        }
        size_t off = (size_t)c * N + j0 + js;
        *(short8*)(hThi + off)     = hi0;
        *(short8*)(hThi + off + 8) = hi1;
        *(short8*)(hTlo + off)     = lo0;
        *(short8*)(hTlo + off + 8) = lo1;
    }
}

// ---------------------------------------------------------------------------
// Kernel 3: nmax = max_j n[j]
// ---------------------------------------------------------------------------
__global__ void k_nmax(const float* __restrict__ n, float* __restrict__ nmax) {
    __shared__ float red[1024];
    int t = threadIdx.x;
    float4 v0 = ((const float4*)n)[t];
    float4 v1 = ((const float4*)n)[t + 1024];
    float m = fmaxf(fmaxf(fmaxf(v0.x, v0.y), fmaxf(v0.z, v0.w)),
                    fmaxf(fmaxf(v1.x, v1.y), fmaxf(v1.z, v1.w)));
    red[t] = m;
    __syncthreads();
    for (int off = 512; off; off >>= 1) {
        if (t < off) red[t] = fmaxf(red[t], red[t + off]);
        __syncthreads();
    }
    if (t == 0) nmax[0] = red[0];
}

// ---------------------------------------------------------------------------
// Kernel 4: fused attention. A AND B staged per 64-j piece via
//   global_load_lds into a double-buffered slab, counted-vmcnt ring
//   (vmcnt(8) steady state, never 0 mid-loop) -> deep HBM pipeline for the
//   A-stream. Loop has NO other VMEM (n pre-staged to LDS, s in regs).
//   Both-sides XOR swizzle on A and B slabs (r8-verified pattern).
//   LDS: A dbuf 32K | B dbuf 32K | n 8K = 72 KB -> 2 blocks/CU.
// ---------------------------------------------------------------------------
__global__ void __launch_bounds__(256, 2) k_main(
        const int* __restrict__ Araw, const float* __restrict__ s,
        const float* __restrict__ n, const float* __restrict__ nmaxp,
        const unsigned short* __restrict__ hThi, const unsigned short* __restrict__ hTlo,
        float* __restrict__ pacc, float* __restrict__ pz) {
    __shared__ __align__(16) char lds[73728];

    const int tid = threadIdx.x;
    const int w = tid >> 6, l = tid & 63;
    const int lr = l & 15, lg = l >> 4;

    const int rbk = blockIdx.x / JSPLIT;
    const int js  = blockIdx.x % JSPLIT;
    const int rblk = rbk * RB;
    const int r0 = rblk + w * 16;
    const int jb = js * JW;

    f32x4 acc0 = {0.f,0.f,0.f,0.f}, acc1 = {0.f,0.f,0.f,0.f};
    f32x4 acc2 = {0.f,0.f,0.f,0.f}, acc3 = {0.f,0.f,0.f,0.f};
    float zacc = 0.0f;

#define STAGE(piece, b)                                                        \
    {                                                                          \
        char* Ad = lds + (b) * 16384;                                          \
        char* Bd = lds + 32768 + (b) * 16384;                                  \
        const int jp = jb + (piece) * PIECE;                                   \
        _Pragma("unroll")                                                      \
        for (int q = 0; q < 4; ++q) {                                          \
            const int arw = q * 16 + (tid >> 4);                               \
            const int acol = ((tid & 15) * 16) ^ ((arw & 7) << 4);             \
            gload_lds16(Araw + (size_t)(rblk + arw) * N + jp + (acol >> 2),    \
                        Ad + q * 4096 + tid * 16);                             \
        }                                                                      \
        _Pragma("unroll")                                                      \
        for (int q = 0; q < 4; ++q) {                                          \
            const int brw = (q & 1) * 32 + (tid >> 3);                         \
            const int bcol = ((tid & 7) * 16) ^ ((brw & 7) << 4);              \
            const unsigned short* srcb =                                       \
                ((q >> 1) ? hTlo : hThi) + (size_t)brw * N + jp + (bcol >> 1); \
            gload_lds16(srcb, Bd + q * 4096 + tid * 16);                       \
        }                                                                      \
    }

    // one K=32 chunk: e-phase from LDS A/n, B-frags from LDS, 12 MFMAs
#define CHUNK(p_, b_, ch_)                                                     \
    {                                                                          \
        const char* Ab = lds + (b_) * 16384;                                   \
        const char* Bb = lds + 32768 + (b_) * 16384;                           \
        const float* nsl = (const float*)(lds + 65536);                        \
        const int swz = (lr & 7) << 4;                                         \
        const int arow = w * 16 + lr;                                          \
        const int acol = (ch_) * 128 + lg * 32;                                \
        int4 av0 = *(const int4*)(Ab + arow * 256 + (acol ^ swz));             \
        int4 av1 = *(const int4*)(Ab + arow * 256 + ((acol + 16) ^ swz));      \
        const float* np0 = nsl + ((p_) * PIECE + (ch_) * 32 + lg * 8);         \
        float4 nv0 = *(const float4*)(np0);                                    \
        float4 nv1 = *(const float4*)(np0 + 4);                                \
        int   av[8] = {av0.x, av0.y, av0.z, av0.w, av1.x, av1.y, av1.z, av1.w};\
        float nf[8] = {nv0.x, nv0.y, nv0.z, nv0.w, nv1.x, nv1.y, nv1.z, nv1.w};\
        short8 ahi, alo;                                                       \
        _Pragma("unroll")                                                      \
        for (int j = 0; j < 8; ++j) {                                          \
            float t  = sval + nf[j];                                           \
            float lv = fmaxf(t, ALPHA * t);                                    \
            float ex = __expf(lv - Mv);                                        \
            ex = (av[j] != 0) ? ex : 0.0f;                                     \
            zacc += ex;                                                        \
            unsigned xb = __float_as_uint(ex);                                 \
            ahi[j] = (short)(xb >> 16);                                        \
            float lof = ex - __uint_as_float(xb & 0xffff0000u);                \
            alo[j] = (short)(__float_as_uint(lof) >> 16);                      \
        }                                                                      \
        const int bcol = ((ch_) * 64 + lg * 16) ^ swz;                         \
        short8 B0h = *(const short8*)(Bb + (lr +  0) * 128 + bcol);            \
        short8 B1h = *(const short8*)(Bb + (lr + 16) * 128 + bcol);            \
        short8 B2h = *(const short8*)(Bb + (lr + 32) * 128 + bcol);            \
        short8 B3h = *(const short8*)(Bb + (lr + 48) * 128 + bcol);            \
        short8 B0l = *(const short8*)(Bb + 8192 + (lr +  0) * 128 + bcol);     \
        short8 B1l = *(const short8*)(Bb + 8192 + (lr + 16) * 128 + bcol);     \
        short8 B2l = *(const short8*)(Bb + 8192 + (lr + 32) * 128 + bcol);     \
        short8 B3l = *(const short8*)(Bb + 8192 + (lr + 48) * 128 + bcol);     \
        acc0 = __builtin_amdgcn_mfma_f32_16x16x32_bf16(ahi, B0h, acc0, 0, 0, 0);\
        acc1 = __builtin_amdgcn_mfma_f32_16x16x32_bf16(ahi, B1h, acc1, 0, 0, 0);\
        acc2 = __builtin_amdgcn_mfma_f32_16x16x32_bf16(ahi, B2h, acc2, 0, 0, 0);\
        acc3 = __builtin_amdgcn_mfma_f32_16x16x32_bf16(ahi, B3h, acc3, 0, 0, 0);\
        acc0 = __builtin_amdgcn_mfma_f32_16x16x32_bf16(ahi, B0l, acc0, 0, 0, 0);\
        acc1 = __builtin_amdgcn_mfma_f32_16x16x32_bf16(ahi, B1l, acc1, 0, 0, 0);\
        acc2 = __builtin_amdgcn_mfma_f32_16x16x32_bf16(ahi, B2l, acc2, 0, 0, 0);\
        acc3 = __builtin_amdgcn_mfma_f32_16x16x32_bf16(ahi, B3l, acc3, 0, 0, 0);\
        acc0 = __builtin_amdgcn_mfma_f32_16x16x32_bf16(alo, B0h, acc0, 0, 0, 0);\
        acc1 = __builtin_amdgcn_mfma_f32_16x16x32_bf16(alo, B1h, acc1, 0, 0, 0);\
        acc2 = __builtin_amdgcn_mfma_f32_16x16x32_bf16(alo, B2h, acc2, 0, 0, 0);\
        acc3 = __builtin_amdgcn_mfma_f32_16x16x32_bf16(alo, B3h, acc3, 0, 0, 0);\
    }

#define COMPUTE(p_, b_) { CHUNK(p_, b_, 0); CHUNK(p_, b_, 1); }

    // ---- prologue: n-slab (2), pieces 0,1 (16) -> 18 outstanding ----
    gload_lds16(n + jb + tid * 4,        lds + 65536 + tid * 16);
    gload_lds16(n + jb + 1024 + tid * 4, lds + 65536 + 4096 + tid * 16);
    STAGE(0, 0);
    STAGE(1, 1);
    const float sval = s[r0 + lr];
    const float tM = sval + nmaxp[0];
    const float Mv = fmaxf(tM, ALPHA * tM);

    asm volatile("s_waitcnt vmcnt(0)" ::: "memory");
    __builtin_amdgcn_sched_barrier(0);
    __builtin_amdgcn_s_barrier();
    __builtin_amdgcn_sched_barrier(0);

    // ---- piece 0 (already waited) ----
    COMPUTE(0, 0);
    __builtin_amdgcn_s_barrier();
    __builtin_amdgcn_sched_barrier(0);
    STAGE(2, 0);

    // ---- steady state: counted vmcnt(8), never drained ----
    for (int p = 1; p < NP - 1; ++p) {
        asm volatile("s_waitcnt vmcnt(8)" ::: "memory");
        __builtin_amdgcn_sched_barrier(0);
        __builtin_amdgcn_s_barrier();
        __builtin_amdgcn_sched_barrier(0);
        COMPUTE(p, p & 1);
        __builtin_amdgcn_s_barrier();
        __builtin_amdgcn_sched_barrier(0);
        if (p < NP - 2) STAGE(p + 2, p & 1);
    }

    // ---- last piece ----
    asm volatile("s_waitcnt vmcnt(0)" ::: "memory");
    __builtin_amdgcn_sched_barrier(0);
    __builtin_amdgcn_s_barrier();
    __builtin_amdgcn_sched_barrier(0);
    COMPUTE(NP - 1, (NP - 1) & 1);

#undef COMPUTE
#undef CHUNK
#undef STAGE

    // ---- z reduce over the 4 k-groups of each row ----
    zacc += __shfl_xor(zacc, 16);
    zacc += __shfl_xor(zacc, 32);

    // ---- write partials ----
    float* pa = pacc + ((size_t)js * N + r0) * NEWF;
#pragma unroll
    for (int r = 0; r < 4; ++r) {
        int row = lg * 4 + r;
        pa[(size_t)row * NEWF +  0 + lr] = acc0[r];
        pa[(size_t)row * NEWF + 16 + lr] = acc1[r];
        pa[(size_t)row * NEWF + 32 + lr] = acc2[r];
        pa[(size_t)row * NEWF + 48 + lr] = acc3[r];
    }
    if (l < 16) pz[(size_t)js * N + r0 + lr] = zacc;
}

// ---------------------------------------------------------------------------
// Kernel 5: finalize — sum partials, divide, relu
// ---------------------------------------------------------------------------
__global__ void k_fin(const float* __restrict__ pacc, const float* __restrict__ pz,
                      float* __restrict__ out) {
    int t = blockIdx.x * 256 + threadIdx.x;     // 0 .. N*NEWF-1
    int i = t >> 6, k = t & 63;
    float v = 0.0f, z = 0.0f;
#pragma unroll
    for (int psl = 0; psl < JSPLIT; ++psl) {
        v += pacc[((size_t)psl * N + i) * NEWF + k];
        z += pz[(size_t)psl * N + i];
    }
    out[t] = fmaxf(v / z, 0.0f);
}

// ---------------------------------------------------------------------------
extern "C" void kernel_launch(void* const* d_in, const int* in_sizes, int n_in,
                              void* d_out, int out_size, void* d_ws, size_t ws_size,
                              hipStream_t stream) {
    const float* X       = (const float*)d_in[0];
    const int*   A       = (const int*)d_in[1];
    const float* W       = (const float*)d_in[2];
    const float* a_self  = (const float*)d_in[3];
    const float* a_neigh = (const float*)d_in[4];
    float* out = (float*)d_out;

    float* wsf = (float*)d_ws;
    float* h    = wsf;                        // N*NEWF f32 (2MB)
    float* s    = h + (size_t)N * NEWF;       // N
    float* nv   = s + N;                      // N
    float* nmax = nv + N;                     // 4
    unsigned short* hThi = (unsigned short*)(nmax + 4);   // N*NEWF ushort (1MB)
    unsigned short* hTlo = hThi + (size_t)N * NEWF;       // N*NEWF ushort (1MB)
    float* pacc = (float*)(hTlo + (size_t)N * NEWF);      // JSPLIT*N*NEWF f32 (8MB)
    float* pz   = pacc + (size_t)JSPLIT * N * NEWF;       // JSPLIT*N f32 (128KB)

    k_hsn <<<N / 4,        256, 0, stream>>>(X, W, a_self, a_neigh, h, s, nv);
    k_tr  <<<N / 64,       256, 0, stream>>>(h, hThi, hTlo);
    k_nmax<<<1,           1024, 0, stream>>>(nv, nmax);
    k_main<<<(N / RB) * JSPLIT, 256, 0, stream>>>(A, s, nv, nmax, hThi, hTlo, pacc, pz);
    k_fin <<<(N * NEWF) / 256, 256, 0, stream>>>(pacc, pz, out);
}